// Round 7
// baseline (190.163 us; speedup 1.0000x reference)
//
#include <hip/hip_runtime.h>
#include <hip/hip_bf16.h>
#include <stdint.h>
#include <stddef.h>

#define D_MODEL 4096
#define RANK    64

typedef __attribute__((ext_vector_type(4)))  float f32x4;
typedef __attribute__((ext_vector_type(16))) float f32x16;
typedef __attribute__((ext_vector_type(8)))  short bf16x8;

__device__ inline short f2bf1(float f) {
    union { __hip_bfloat16 t; short s; } c;
    c.t = __float2bfloat16(f);
    return c.s;
}
__device__ inline uint32_t pkbf(float a, float b) {
    union { __hip_bfloat162 t; uint32_t u; } c;
    c.t = __float22bfloat162_rn(make_float2(a, b));
    return c.u;
}

// ---------------------------------------------------------------------------
// Dequant + pack both weights into MFMA-fragment order (round-4 layouts).
// apk (16x16x32 B-frag): apk[((kb*4+n)*64+l)*8+j] = a[16n+(l&15)][kb*32+(l>>4)*8+j]
// bpk (32x32x16 B-frag): bpk[((cb*4+ks)*64+l)*8+j] = b[cb*32+(l&31)][ks*16+(l>>5)*8+j]
// ---------------------------------------------------------------------------
__global__ __launch_bounds__(256) void dequant_pack_kernel(
        const int* __restrict__ qa, const float* __restrict__ qas,
        const int* __restrict__ qb, const float* __restrict__ qbs,
        short* __restrict__ apk, short* __restrict__ bpk) {
    const int idx = blockIdx.x * 256 + threadIdx.x;   // 0..32767
    const int l = idx & 63, t = idx >> 6;             // t: 0..511
    {   // a-side: t -> (kb 0..127, n 0..3)
        const int n = t & 3, kb = t >> 2;
        const int r = 16 * n + (l & 15);
        const int kbase = kb * 32 + ((l >> 4) << 3);
        const int* q = qa + (size_t)r * D_MODEL + kbase;
        const float s = qas[r * (D_MODEL / 32) + kb];
        bf16x8 o;
        #pragma unroll
        for (int j = 0; j < 8; ++j) o[j] = f2bf1((float)q[j] * s);
        *(bf16x8*)(apk + (size_t)idx * 8) = o;
    }
    {   // b-side: t -> (cb 0..127, ks 0..3)
        const int ks = t & 3, cb = t >> 2;
        const int d = cb * 32 + (l & 31);
        const int rbase = ks * 16 + ((l >> 5) << 3);
        const int* q = qb + (size_t)d * RANK + rbase;
        const float s = qbs[d * 2 + (ks >> 1)];
        bf16x8 o;
        #pragma unroll
        for (int j = 0; j < 8; ++j) o[j] = f2bf1((float)q[j] * s);
        *(bf16x8*)(bpk + (size_t)idx * 8) = o;
    }
}

// ---------------------------------------------------------------------------
// Stage 1: h[T][64] = x[T][4096] @ a^T. Block = 16 rows, 4 waves; wave w
// free-runs its k-slice [w*1024, +1024) with NO barriers in the loop;
// unroll 8 keeps ~16 f32x4 x-loads in flight per wave continuously.
// One LDS reduce + h store at the end.
// ---------------------------------------------------------------------------
__global__ __launch_bounds__(256, 4) void stage1_kernel(
        const float* __restrict__ x, const short* __restrict__ apk,
        short* __restrict__ h) {
    const int tid  = threadIdx.x;
    const int lane = tid & 63;
    const int wave = tid >> 6;
    const int rb   = blockIdx.x * 16;

    const int row16 = lane & 15;
    const int ko8   = (lane >> 4) << 3;          // 0,8,16,24

    const float* xp = x + (size_t)(rb + row16) * D_MODEL + wave * 1024 + ko8;
    const short* ap = apk + ((size_t)(wave * 32) * 4 * 64) * 8;

    f32x4 acc[4];
    #pragma unroll
    for (int n = 0; n < 4; ++n) acc[n] = (f32x4){0.f, 0.f, 0.f, 0.f};

    #pragma unroll 8
    for (int s = 0; s < 32; ++s) {
        f32x4 xv0 = *(const f32x4*)(xp + s * 32);
        f32x4 xv1 = *(const f32x4*)(xp + s * 32 + 4);
        bf16x8 af;
        uint32_t* afu = (uint32_t*)&af;
        afu[0] = pkbf(xv0[0], xv0[1]);
        afu[1] = pkbf(xv0[2], xv0[3]);
        afu[2] = pkbf(xv1[0], xv1[1]);
        afu[3] = pkbf(xv1[2], xv1[3]);
        #pragma unroll
        for (int n = 0; n < 4; ++n) {
            bf16x8 bf = *(const bf16x8*)(ap + (((size_t)s * 4 + n) * 64 + lane) * 8);
            acc[n] = __builtin_amdgcn_mfma_f32_16x16x32_bf16(af, bf, acc[n], 0, 0, 0);
        }
    }

    // cross-wave reduction (one barrier)
    __shared__ float red[4][16][68];
    const int r4 = (lane >> 4) << 2;
    #pragma unroll
    for (int n = 0; n < 4; ++n)
        #pragma unroll
        for (int j = 0; j < 4; ++j)
            red[wave][r4 + j][n * 16 + row16] = acc[n][j];
    __syncthreads();

    // 1024 elems, 256 threads: thread t -> row t>>4, cols (t&15)*4..+4
    {
        const int r = tid >> 4, c0 = (tid & 15) << 2;
        union { short s[4]; uint2 u; } o;
        #pragma unroll
        for (int j = 0; j < 4; ++j) {
            float s = red[0][r][c0 + j] + red[1][r][c0 + j]
                    + red[2][r][c0 + j] + red[3][r][c0 + j];
            o.s[j] = f2bf1(s);
        }
        *(uint2*)(h + (size_t)(rb + r) * RANK + c0) = o.u;
    }
}

// ---------------------------------------------------------------------------
// Stage 2: out[T][4096] = h[T][64] @ b^T. Wave = 32 rows x 128 cols
// (4 x 32x32 tiles), block = 4 waves side-by-side in N. Grid (T/32, 8).
// h and bpk are L2/L3-resident; stores are full 128B segments.
// ---------------------------------------------------------------------------
__global__ __launch_bounds__(256) void stage2_kernel(
        const short* __restrict__ h, const short* __restrict__ bpk,
        float* __restrict__ out) {
    const int lane = threadIdx.x & 63;
    const int wave = threadIdx.x >> 6;
    const int rb = blockIdx.x * 32;
    const int cb32 = blockIdx.y * 16 + wave * 4;       // first 32-col tile idx

    const short* hp = h + (size_t)(rb + (lane & 31)) * RANK + ((lane >> 5) << 3);

    bf16x8 hf[4];
    #pragma unroll
    for (int k0 = 0; k0 < 4; ++k0)
        hf[k0] = *(const bf16x8*)(hp + k0 * 16);

    #pragma unroll
    for (int t = 0; t < 4; ++t) {
        const int cb = cb32 + t;
        f32x16 acc;
        #pragma unroll
        for (int j = 0; j < 16; ++j) acc[j] = 0.f;
        #pragma unroll
        for (int ks = 0; ks < 4; ++ks) {
            bf16x8 bf = *(const bf16x8*)(bpk + (((size_t)cb * 4 + ks) * 64 + lane) * 8);
            acc = __builtin_amdgcn_mfma_f32_32x32x16_bf16(hf[ks], bf, acc, 0, 0, 0);
        }
        const int col = cb * 32 + (lane & 31);
        #pragma unroll
        for (int reg = 0; reg < 16; ++reg) {
            const int r = (reg & 3) + 8 * (reg >> 2) + ((lane >> 5) << 2);
            out[(size_t)(rb + r) * D_MODEL + col] = acc[reg];
        }
    }
}

// ---------------------------------------------------------------------------
extern "C" void kernel_launch(void* const* d_in, const int* in_sizes, int n_in,
                              void* d_out, int out_size, void* d_ws, size_t ws_size,
                              hipStream_t stream) {
    (void)n_in; (void)out_size; (void)ws_size;
    const float* x   = (const float*)d_in[0];
    const int*   qa  = (const int*)d_in[1];
    const float* qas = (const float*)d_in[2];
    const int*   qb  = (const int*)d_in[3];
    const float* qbs = (const float*)d_in[4];
    float* out = (float*)d_out;

    const int T = in_sizes[0] / D_MODEL;   // 16384

    short* apk = (short*)d_ws;                       // 64*4096 bf16 packed
    short* bpk = apk + (size_t)RANK * D_MODEL;       // 4096*64 bf16 packed
    short* h   = bpk + (size_t)D_MODEL * RANK;       // T*64 bf16

    dequant_pack_kernel<<<128, 256, 0, stream>>>(qa, qas, qb, qbs, apk, bpk);
    stage1_kernel<<<T / 16, 256, 0, stream>>>(x, apk, h);
    dim3 g2(T / 32, D_MODEL / 512);
    stage2_kernel<<<g2, 256, 0, stream>>>(h, bpk, out);
}

// Round 9
// 148.530 us; speedup vs baseline: 1.2803x; 1.2803x over previous
//
#include <hip/hip_runtime.h>
#include <hip/hip_bf16.h>
#include <stdint.h>
#include <stddef.h>

#define D_MODEL 4096
#define RANK    64
#define M_BLK   64
#define KC      128                  // fp32 k per chunk
#define NCHK    (D_MODEL / KC)       // 32
#define BUFB    32768                // bytes per ring buffer (64 rows x 128 f32 x 4B)

typedef __attribute__((ext_vector_type(4)))  float f32x4;
typedef __attribute__((ext_vector_type(16))) float f32x16;
typedef __attribute__((ext_vector_type(8)))  short bf16x8;

__device__ inline short f2bf1(float f) {
    union { __hip_bfloat16 t; short s; } c;
    c.t = __float2bfloat16(f);
    return c.s;
}
__device__ inline uint32_t pkbf(float a, float b) {
    union { __hip_bfloat162 t; uint32_t u; } c;
    c.t = __float22bfloat162_rn(make_float2(a, b));
    return c.u;
}

// global -> LDS direct copy, 16 B per lane. LDS base must be wave-uniform;
// hardware writes lds_base + lane*16. Global address is per-lane.
__device__ inline void gload_lds16(const void* g, void* l) {
    __builtin_amdgcn_global_load_lds(
        (const __attribute__((address_space(1))) uint32_t*)g,
        (__attribute__((address_space(3))) uint32_t*)l, 16, 0, 0);
}

// ---------------------------------------------------------------------------
// Dequant + pack both weights into MFMA-fragment order (as round 4).
// apk (16x16x32 B-frag): apk[((kb*4+n)*64+l)*8+j] = a[16n+(l&15)][kb*32+(l>>4)*8+j]
// bpk (32x32x16 B-frag): bpk[((cb*4+ks)*64+l)*8+j] = b[cb*32+(l&31)][ks*16+(l>>5)*8+j]
// ---------------------------------------------------------------------------
__global__ __launch_bounds__(256) void dequant_pack_kernel(
        const int* __restrict__ qa, const float* __restrict__ qas,
        const int* __restrict__ qb, const float* __restrict__ qbs,
        short* __restrict__ apk, short* __restrict__ bpk) {
    const int idx = blockIdx.x * 256 + threadIdx.x;   // 0..32767
    const int l = idx & 63, t = idx >> 6;             // t: 0..511
    {   // a-side: t -> (kb 0..127, n 0..3)
        const int n = t & 3, kb = t >> 2;
        const int r = 16 * n + (l & 15);
        const int kbase = kb * 32 + ((l >> 4) << 3);
        const int* q = qa + (size_t)r * D_MODEL + kbase;
        const float s = qas[r * (D_MODEL / 32) + kb];
        bf16x8 o;
        #pragma unroll
        for (int j = 0; j < 8; ++j) o[j] = f2bf1((float)q[j] * s);
        *(bf16x8*)(apk + (size_t)idx * 8) = o;
    }
    {   // b-side: t -> (cb 0..127, ks 0..3)
        const int ks = t & 3, cb = t >> 2;
        const int d = cb * 32 + (l & 31);
        const int rbase = ks * 16 + ((l >> 5) << 3);
        const int* q = qb + (size_t)d * RANK + rbase;
        const float s = qbs[d * 2 + (ks >> 1)];
        bf16x8 o;
        #pragma unroll
        for (int j = 0; j < 8; ++j) o[j] = f2bf1((float)q[j] * s);
        *(bf16x8*)(bpk + (size_t)idx * 8) = o;
    }
}

// ---------------------------------------------------------------------------
// Fused producer/consumer kernel. Block = 64 token rows, 512 thr = 8 waves,
// grid 256 (= 1 block/CU). Waves 0-3 produce: global_load_lds x fp32 into a
// 4-deep LDS ring, counted vmcnt, raw barriers. Waves 4-7 consume: swizzled
// ds_read_b128 -> cvt -> 16x16x32 MFMA with only L2 apk loads in their vmcnt.
//
// Ring schedule (race-free; R8's bug was issue-before-barrier = 4-ahead):
//   prologue: issue chunks 0,1,2
//   iter i:   waitcnt(chunk i landed) -> s_barrier -> issue chunk i+3
// In window (b_i, b_{i+1}): consumer reads buf i&3; writes in flight are
// chunks i+1,i+2,i+3 -> bufs (i+1..i+3)&3, all distinct from i&3, and
// chunk i+3's buffer was released by the consumer at barrier i.
//
// LDS x layout (per chunk buffer, linear for gll): row-major [64][128] f32;
// each row's 32 16B-slots permuted: slot s of row r holds k-group s^(r&7).
// Producers pre-swizzle the GLOBAL source; consumers XOR on read (T21).
// ---------------------------------------------------------------------------
__global__ __launch_bounds__(512) void fused_kernel(
        const float* __restrict__ x, const short* __restrict__ apk,
        const short* __restrict__ bpk, float* __restrict__ out) {
    __shared__ __align__(16) char smem[4 * BUFB + 8192];
    float* red   = (float*)smem;                 // [4][64][68] overlay, 69632 B
    char*  h_lds = smem + 4 * BUFB;              // [64][64] bf16, slot-swizzled

    const int tid  = threadIdx.x;
    const int lane = tid & 63;
    const int wave = tid >> 6;
    const int rb   = blockIdx.x * M_BLK;
    const float* xb = x + (size_t)rb * D_MODEL;

    f32x4 acc[4][4];
    #pragma unroll
    for (int m = 0; m < 4; ++m)
        #pragma unroll
        for (int n = 0; n < 4; ++n) acc[m][n] = (f32x4){0.f, 0.f, 0.f, 0.f};

    if (wave < 4) {
        // ================= producers =================
        // instr j (j = wave*8+jj) covers rows 2j, 2j+1: lane l -> row 2j+(l>>5),
        // slot l&31; global k-group = (l&31) ^ (row&7)  (pre-swizzle).
        const int row2 = 2 * (wave * 8) + (lane >> 5);     // row of jj=0
        #define ISSUE_CHUNK(c)                                                  \
        {                                                                       \
            char* ldsb = smem + ((c) & 3) * BUFB + (wave * 8) * 1024;           \
            _Pragma("unroll")                                                   \
            for (int jj = 0; jj < 8; ++jj) {                                    \
                const int rw = row2 + 2 * jj;                                   \
                const int k4 = ((lane & 31) ^ (rw & 7)) << 2;                   \
                const float* src = xb + (size_t)rw * D_MODEL + (c) * KC + k4;   \
                gload_lds16(src, ldsb + jj * 1024);                             \
            }                                                                   \
        }
        ISSUE_CHUNK(0)
        ISSUE_CHUNK(1)
        ISSUE_CHUNK(2)
        for (int i = 0; i < NCHK; ++i) {
            // ensure chunk i has landed; keep chunks i+1, i+2 in flight
            if (i < NCHK - 2)       asm volatile("s_waitcnt vmcnt(16)" ::: "memory");
            else if (i == NCHK - 2) asm volatile("s_waitcnt vmcnt(8)"  ::: "memory");
            else                    asm volatile("s_waitcnt vmcnt(0)"  ::: "memory");
            __builtin_amdgcn_s_barrier();
            asm volatile("" ::: "memory");
            if (i + 3 < NCHK) ISSUE_CHUNK(i + 3)
        }
        #undef ISSUE_CHUNK
    } else {
        // ================= consumers =================
        const int cw = wave - 4;
        for (int i = 0; i < NCHK; ++i) {
            asm volatile("" ::: "memory");
            __builtin_amdgcn_s_barrier();
            asm volatile("" ::: "memory");
            const char* bufc = smem + (i & 3) * BUFB;
            bf16x8 af[4];
            #pragma unroll
            for (int m = 0; m < 4; ++m) {
                const int row = m * 16 + (lane & 15);
                const int s0  = cw * 8 + ((lane >> 4) << 1);
                f32x4 lo = *(const f32x4*)(bufc + row * 512 + ((s0 ^ (row & 7)) << 4));
                f32x4 hi = *(const f32x4*)(bufc + row * 512 + (((s0 + 1) ^ (row & 7)) << 4));
                uint32_t* p = (uint32_t*)&af[m];
                p[0] = pkbf(lo[0], lo[1]); p[1] = pkbf(lo[2], lo[3]);
                p[2] = pkbf(hi[0], hi[1]); p[3] = pkbf(hi[2], hi[3]);
            }
            const int kbg = i * 4 + cw;
            #pragma unroll
            for (int n = 0; n < 4; ++n) {
                bf16x8 bf = *(const bf16x8*)(apk + ((size_t)(kbg * 4 + n) * 64 + lane) * 8);
                #pragma unroll
                for (int m = 0; m < 4; ++m)
                    acc[m][n] = __builtin_amdgcn_mfma_f32_16x16x32_bf16(
                        af[m], bf, acc[m][n], 0, 0, 0);
            }
            // all LDS reads of this buffer definitely complete before the
            // producer can overwrite it (issued only after the NEXT barrier)
            asm volatile("s_waitcnt lgkmcnt(0)" ::: "memory");
        }
    }

    __syncthreads();                      // ring fully consumed; reuse as red

    // ---- phase 2: consumer partials -> red, all-thread reduce -> h_lds ----
    if (wave >= 4) {
        const int cw = wave - 4;
        const int r4 = (lane >> 4) << 2;
        #pragma unroll
        for (int m = 0; m < 4; ++m)
            #pragma unroll
            for (int n = 0; n < 4; ++n)
                #pragma unroll
                for (int j = 0; j < 4; ++j)
                    red[((size_t)cw * 64 + m * 16 + r4 + j) * 68 + n * 16 + (lane & 15)] =
                        acc[m][n][j];
    }
    __syncthreads();
    {
        const int r = tid >> 3, sl = tid & 7;   // row 0..63, slot 0..7 (8 f32)
        const int c0 = sl << 3;
        float s[8];
        #pragma unroll
        for (int u = 0; u < 8; ++u)
            s[u] = red[(0 * 64 + r) * 68 + c0 + u] + red[(1 * 64 + r) * 68 + c0 + u]
                 + red[(2 * 64 + r) * 68 + c0 + u] + red[(3 * 64 + r) * 68 + c0 + u];
        uint4 o;
        o.x = pkbf(s[0], s[1]); o.y = pkbf(s[2], s[3]);
        o.z = pkbf(s[4], s[5]); o.w = pkbf(s[6], s[7]);
        *(uint4*)(h_lds + r * 128 + ((sl ^ (r & 7)) << 4)) = o;
    }
    __syncthreads();

    // ---- phase 3: out[64][4096] = h @ b^T; wave w -> cols [w*512, +512) ----
    bf16x8 hf[2][4];
    #pragma unroll
    for (int m = 0; m < 2; ++m)
        #pragma unroll
        for (int ks = 0; ks < 4; ++ks) {
            const int row  = m * 32 + (lane & 31);
            const int slot = ks * 2 + (lane >> 5);
            hf[m][ks] = *(const bf16x8*)(h_lds + row * 128 + ((slot ^ (row & 7)) << 4));
        }

    #pragma unroll 2
    for (int n = 0; n < 16; ++n) {
        const int cb = wave * 16 + n;              // 32-col tile index
        f32x16 a2[2];
        #pragma unroll
        for (int m = 0; m < 2; ++m)
            #pragma unroll
            for (int j = 0; j < 16; ++j) a2[m][j] = 0.f;
        #pragma unroll
        for (int ks = 0; ks < 4; ++ks) {
            bf16x8 bf = *(const bf16x8*)(bpk + ((size_t)(cb * 4 + ks) * 64 + lane) * 8);
            #pragma unroll
            for (int m = 0; m < 2; ++m)
                a2[m] = __builtin_amdgcn_mfma_f32_32x32x16_bf16(hf[m][ks], bf, a2[m], 0, 0, 0);
        }
        const int col = cb * 32 + (lane & 31);
        #pragma unroll
        for (int m = 0; m < 2; ++m)
            #pragma unroll
            for (int reg = 0; reg < 16; ++reg) {
                const int r = m * 32 + (reg & 3) + 8 * (reg >> 2) + ((lane >> 5) << 2);
                out[(size_t)(rb + r) * D_MODEL + col] = a2[m][reg];
            }
    }
}

// ---------------------------------------------------------------------------
extern "C" void kernel_launch(void* const* d_in, const int* in_sizes, int n_in,
                              void* d_out, int out_size, void* d_ws, size_t ws_size,
                              hipStream_t stream) {
    (void)n_in; (void)out_size; (void)ws_size;
    const float* x   = (const float*)d_in[0];
    const int*   qa  = (const int*)d_in[1];
    const float* qas = (const float*)d_in[2];
    const int*   qb  = (const int*)d_in[3];
    const float* qbs = (const float*)d_in[4];
    float* out = (float*)d_out;

    const int T = in_sizes[0] / D_MODEL;   // 16384

    short* apk = (short*)d_ws;                       // 64*4096 bf16 packed
    short* bpk = apk + (size_t)RANK * D_MODEL;       // 4096*64 bf16 packed

    dequant_pack_kernel<<<128, 256, 0, stream>>>(qa, qas, qb, qbs, apk, bpk);
    fused_kernel<<<T / M_BLK, 512, 0, stream>>>(x, apk, bpk, out);
}